// Round 20
// baseline (343.949 us; speedup 1.0000x reference)
//
#include <hip/hip_runtime.h>
#include <hip/hip_bf16.h>
#include <math.h>

typedef __attribute__((ext_vector_type(4))) float  f32x4;
typedef __attribute__((ext_vector_type(8))) __bf16 bf16x8;
typedef __attribute__((ext_vector_type(4))) __bf16 bf16x4;
typedef __attribute__((ext_vector_type(4))) short  s16x4;

#define SCL 0.18033688011111543f   // 0.125 * log2(e)
#define MFMA16(a, b, c)   __builtin_amdgcn_mfma_f32_16x16x32_bf16((a), (b), (c), 0, 0, 0)
#define MFMA16K16(a, b, c) __builtin_amdgcn_mfma_f32_16x16x16bf16_1k((a), (b), (c), 0, 0, 0)

union B4 { bf16x4 b; s16x4 s; };

__device__ __forceinline__ float exp2_fast(float x) {
    float r;
    asm("v_exp_f32 %0, %1" : "=v"(r) : "v"(x));
    return r;
}

// ---------------- combined pack: Wq/Wk transpose + WvT/WoT/bvP ---------------
__global__ __launch_bounds__(256) void pack_all(
    const float* __restrict__ Wq, const float* __restrict__ Wk,
    const float* __restrict__ Wv, const float* __restrict__ bv,
    const float* __restrict__ Wo,
    __bf16* __restrict__ WqT, __bf16* __restrict__ WkT,
    __bf16* __restrict__ WvT, float* __restrict__ bvP, __bf16* __restrict__ WoT)
{
    const int tid = threadIdx.x;
    if (blockIdx.x >= 256) {          // misc packs
        int idx = (blockIdx.x - 256) * 256 + tid;
        if (idx < 131072) {
            int n = idx >> 10, k = idx & 1023;
            WvT[idx] = (n < 64) ? (__bf16)Wv[k * 64 + n] : (__bf16)0.0f;
        }
        if (idx < 65536) {
            int n = idx >> 6, d = idx & 63;
            WoT[idx] = (__bf16)Wo[d * 1024 + n];
        }
        if (idx < 128) bvP[idx] = (idx < 64) ? bv[idx] : 0.0f;
        return;
    }
    __shared__ __bf16 T0[64][68];
    __shared__ __bf16 T1[64][68];
    const int h = blockIdx.x & 15, kt = blockIdx.x >> 4;   // 256 blocks
    const int kk = tid >> 2, cf = (tid & 3) * 16;
    const size_t base = (size_t)h * 65536 + (size_t)(kt * 64 + kk) * 64 + cf;
    #pragma unroll
    for (int j = 0; j < 4; ++j) {
        f32x4 v = *(const f32x4*)&Wq[base + 4 * j];
        f32x4 u = *(const f32x4*)&Wk[base + 4 * j];
        bf16x4 vb, ub;
        #pragma unroll
        for (int e = 0; e < 4; ++e) { vb[e] = (__bf16)v[e]; ub[e] = (__bf16)u[e]; }
        *(bf16x4*)&T0[kk][cf + 4 * j] = vb;
        *(bf16x4*)&T1[kk][cf + 4 * j] = ub;
    }
    __syncthreads();
    const int c = tid >> 2, k8 = (tid & 3) * 16;
    bf16x8 q0, q1, k0v, k1v;
    #pragma unroll
    for (int j = 0; j < 8; ++j) {
        q0[j] = T0[k8 + j][c];     q1[j] = T0[k8 + 8 + j][c];
        k0v[j] = T1[k8 + j][c];    k1v[j] = T1[k8 + 8 + j][c];
    }
    size_t dst = (size_t)(h * 64 + c) * 1024 + kt * 64 + k8;
    *(bf16x8*)&WqT[dst] = q0;  *(bf16x8*)&WqT[dst + 8] = q1;
    *(bf16x8*)&WkT[dst] = k0v; *(bf16x8*)&WkT[dst + 8] = k1v;
}

// ---------------- Q+K projection: single-buffer BK=64, 4 blocks/CU ----------
// m97/m151 2-barrier structure with reg staging: LDS 36.9KB (vs dbuf 73.7KB)
// -> 4 blocks/CU, 4 staggered barrier domains; full BK=64 prefetch distance.
__global__ __launch_bounds__(256, 4) void proj_qk(
    const float* __restrict__ Aq, const float* __restrict__ Ak,
    const __bf16* __restrict__ WqT, const __bf16* __restrict__ WkT,
    const float* __restrict__ bq, const float* __restrict__ bk,
    __bf16* __restrict__ Cq, __bf16* __restrict__ Ck)
{
    const int z = blockIdx.z;
    const float* A  = z ? Ak : Aq;
    const __bf16* Bt = z ? WkT : WqT;
    const float* bias = z ? bk : bq;
    __bf16* C = z ? Ck : Cq;
    const float oscale = z ? 1.0f : SCL;

    __shared__ __bf16 As[128][72];
    __shared__ __bf16 Bs[128][72];

    const int tid = threadIdx.x;
    const int lane = tid & 63, w = tid >> 6;
    const int wr = w >> 1, wc = w & 1;
    const int l15 = lane & 15, g = lane >> 4;
    const int m0 = blockIdx.x * 128, n0 = blockIdx.y * 128;
    const int arow = tid >> 4, acf = (tid & 15) * 4;
    const int brow = tid >> 3, bc8 = (tid & 7) * 8;

    f32x4 areg[8];
    bf16x8 breg[4];
    #pragma unroll
    for (int p = 0; p < 8; ++p)
        areg[p] = *(const f32x4*)&A[(size_t)(m0 + arow + 16 * p) * 1024 + acf];
    #pragma unroll
    for (int p = 0; p < 4; ++p)
        breg[p] = *(const bf16x8*)&Bt[(size_t)(n0 + brow + 32 * p) * 1024 + bc8];

    f32x4 acc[4][4] = {};
    for (int k0 = 0; k0 < 1024; k0 += 64) {
        // stage current tile from regs
        #pragma unroll
        for (int p = 0; p < 8; ++p) {
            bf16x4 c4;
            #pragma unroll
            for (int e = 0; e < 4; ++e) c4[e] = (__bf16)areg[p][e];
            *(bf16x4*)&As[arow + 16 * p][acf] = c4;
        }
        #pragma unroll
        for (int p = 0; p < 4; ++p)
            *(bf16x8*)&Bs[brow + 32 * p][bc8] = breg[p];
        // prefetch next tile (latency hides under compute below)
        if (k0 < 960) {
            #pragma unroll
            for (int p = 0; p < 8; ++p)
                areg[p] = *(const f32x4*)&A[(size_t)(m0 + arow + 16 * p) * 1024 + k0 + 64 + acf];
            #pragma unroll
            for (int p = 0; p < 4; ++p)
                breg[p] = *(const bf16x8*)&Bt[(size_t)(n0 + brow + 32 * p) * 1024 + k0 + 64 + bc8];
        }
        __syncthreads();
        __builtin_amdgcn_s_setprio(1);
        #pragma unroll
        for (int ks = 0; ks < 2; ++ks) {
            bf16x8 af[4], bfv[4];
            #pragma unroll
            for (int mi = 0; mi < 4; ++mi)
                af[mi] = *(const bf16x8*)&As[64 * wr + 16 * mi + l15][32 * ks + 8 * g];
            #pragma unroll
            for (int ni = 0; ni < 4; ++ni)
                bfv[ni] = *(const bf16x8*)&Bs[64 * wc + 16 * ni + l15][32 * ks + 8 * g];
            #pragma unroll
            for (int mi = 0; mi < 4; ++mi)
                #pragma unroll
                for (int ni = 0; ni < 4; ++ni)
                    acc[mi][ni] = MFMA16(af[mi], bfv[ni], acc[mi][ni]);
        }
        __builtin_amdgcn_s_setprio(0);
        __syncthreads();   // protect LDS before next-iter overwrite
    }

    #pragma unroll
    for (int mi = 0; mi < 4; ++mi)
        #pragma unroll
        for (int ni = 0; ni < 4; ++ni) {
            int n = n0 + 64 * wc + 16 * ni + l15;
            float bn = bias[n];
            #pragma unroll
            for (int r = 0; r < 4; ++r) {
                int m = m0 + 64 * wr + 16 * mi + 4 * g + r;
                C[(size_t)m * 1024 + n] = (__bf16)((acc[mi][ni][r] + bn) * oscale);
            }
        }
}

// ---------------- V projection: BM=64, BN=64, transposed store (V^T) --------
__global__ __launch_bounds__(256, 2) void proj_v(
    const float* __restrict__ A, const __bf16* __restrict__ Bt,
    const float* __restrict__ bias, __bf16* __restrict__ C)
{
    __shared__ __bf16 As[2][64][72];
    __shared__ __bf16 Bs[2][64][72];

    const int tid = threadIdx.x;
    const int lane = tid & 63, w = tid >> 6;
    const int wr = w >> 1, wc = w & 1;
    const int l15 = lane & 15, g = lane >> 4;
    const int m0 = blockIdx.x * 64;
    const int arow = tid >> 2, acf = (tid & 3) * 16;
    const int bcf = (tid & 3) * 16;

    f32x4 areg[4];
    bf16x8 breg[2];
    #pragma unroll
    for (int j = 0; j < 4; ++j)
        areg[j] = *(const f32x4*)&A[(size_t)(m0 + arow) * 1024 + acf + 4 * j];
    #pragma unroll
    for (int j = 0; j < 2; ++j)
        breg[j] = *(const bf16x8*)&Bt[(size_t)arow * 1024 + bcf + 8 * j];

    f32x4 acc[2][2] = {};
    int cur = 0;
    for (int k0 = 0; k0 < 1024; k0 += 64) {
        #pragma unroll
        for (int j = 0; j < 4; ++j) {
            bf16x4 c4;
            #pragma unroll
            for (int e = 0; e < 4; ++e) c4[e] = (__bf16)areg[j][e];
            *(bf16x4*)&As[cur][arow][acf + 4 * j] = c4;
        }
        #pragma unroll
        for (int j = 0; j < 2; ++j)
            *(bf16x8*)&Bs[cur][arow][bcf + 8 * j] = breg[j];
        if (k0 < 960) {
            #pragma unroll
            for (int j = 0; j < 4; ++j)
                areg[j] = *(const f32x4*)&A[(size_t)(m0 + arow) * 1024 + k0 + 64 + acf + 4 * j];
            #pragma unroll
            for (int j = 0; j < 2; ++j)
                breg[j] = *(const bf16x8*)&Bt[(size_t)arow * 1024 + k0 + 64 + bcf + 8 * j];
        }
        __syncthreads();
        #pragma unroll
        for (int ks = 0; ks < 2; ++ks) {
            bf16x8 af[2], bfv[2];
            #pragma unroll
            for (int mi = 0; mi < 2; ++mi)
                af[mi] = *(const bf16x8*)&As[cur][32 * wr + 16 * mi + l15][32 * ks + 8 * g];
            #pragma unroll
            for (int ni = 0; ni < 2; ++ni)
                bfv[ni] = *(const bf16x8*)&Bs[cur][32 * wc + 16 * ni + l15][32 * ks + 8 * g];
            #pragma unroll
            for (int mi = 0; mi < 2; ++mi)
                #pragma unroll
                for (int ni = 0; ni < 2; ++ni)
                    acc[mi][ni] = MFMA16(af[mi], bfv[ni], acc[mi][ni]);
        }
        __syncthreads();
        cur ^= 1;
    }

    #pragma unroll
    for (int mi = 0; mi < 2; ++mi)
        #pragma unroll
        for (int ni = 0; ni < 2; ++ni) {
            int n = 32 * wc + 16 * ni + l15;
            float bn = bias[n];
            #pragma unroll
            for (int r = 0; r < 4; ++r) {
                int m = m0 + 32 * wr + 16 * mi + 4 * g + r;
                C[(size_t)n * 8192 + m] = (__bf16)(acc[mi][ni][r] + bn);   // V^T
            }
        }
}

// ---------------- fused attention: R8-exact (LDS V stride 44), v_exp_f32 ----
__global__ __launch_bounds__(128, 4) void attn_kernel(
    const __bf16* __restrict__ Qb, const __bf16* __restrict__ Kb,
    const __bf16* __restrict__ Vt, __bf16* __restrict__ Oh)
{
    __shared__ __bf16 Ks[2][32][68];     // 34-dword stride
    __shared__ __bf16 Vs[2][64][44];     // 22-dword stride (proven best, R8)

    const int qt = blockIdx.x, bh = blockIdx.y;
    const int b = bh >> 4, h = bh & 15;
    const int tid = threadIdx.x;
    const int lane = tid & 63, w = tid >> 6;       // 2 waves
    const int l15 = lane & 15, g = lane >> 4;
    const int s0 = b * 1024 + qt * 64;

    const int krow = tid >> 2, kc = (tid & 3) * 16;   // K: 32 rows, 4 thr/row
    const int vrow = tid >> 1, vc = (tid & 1) * 16;   // V: 64 rows, 2 thr/row

    // Q fragments (wave owns 32 q-rows); Q pre-scaled by 0.125*log2(e)
    bf16x8 qf[2][2];
    #pragma unroll
    for (int mi = 0; mi < 2; ++mi)
        #pragma unroll
        for (int ks = 0; ks < 2; ++ks)
            qf[mi][ks] = *(const bf16x8*)
                &Qb[(size_t)(s0 + 32 * w + 16 * mi + l15) * 1024 + h * 64 + 32 * ks + 8 * g];

    const __bf16* Kbase = Kb + (size_t)(b * 1024) * 1024 + h * 64;
    const __bf16* Vbase = Vt + (size_t)b * 1024;

    bf16x8 kreg[2], vreg[2];
    #pragma unroll
    for (int j = 0; j < 2; ++j) {
        kreg[j] = *(const bf16x8*)&Kbase[(size_t)krow * 1024 + kc + 8 * j];
        vreg[j] = *(const bf16x8*)&Vbase[(size_t)vrow * 8192 + vc + 8 * j];
    }

    f32x4 acc_o[2][4] = {};
    float l_par[2] = {0.0f, 0.0f};

    int cur = 0;
    for (int it = 0; it < 32; ++it) {
        *(bf16x8*)&Ks[cur][krow][kc]     = kreg[0];
        *(bf16x8*)&Ks[cur][krow][kc + 8] = kreg[1];
        *(bf16x8*)&Vs[cur][vrow][vc]     = vreg[0];
        *(bf16x8*)&Vs[cur][vrow][vc + 8] = vreg[1];
        if (it < 31) {
            int t1 = (it + 1) * 32;
            #pragma unroll
            for (int j = 0; j < 2; ++j) {
                kreg[j] = *(const bf16x8*)&Kbase[(size_t)(t1 + krow) * 1024 + kc + 8 * j];
                vreg[j] = *(const bf16x8*)&Vbase[(size_t)vrow * 8192 + t1 + vc + 8 * j];
            }
        }
        __syncthreads();

        // S^T[t][q] = sum_d K[t][d] Q[q][d]   (already log2-scaled via Q)
        f32x4 pacc[2][2] = {};
        __builtin_amdgcn_s_setprio(1);
        #pragma unroll
        for (int ks = 0; ks < 2; ++ks) {
            bf16x8 kf[2];
            #pragma unroll
            for (int ni = 0; ni < 2; ++ni)
                kf[ni] = *(const bf16x8*)&Ks[cur][16 * ni + l15][32 * ks + 8 * g];
            #pragma unroll
            for (int mi = 0; mi < 2; ++mi)
                #pragma unroll
                for (int ni = 0; ni < 2; ++ni)
                    pacc[mi][ni] = MFMA16(kf[ni], qf[mi][ks], pacc[mi][ni]);
        }
        __builtin_amdgcn_s_setprio(0);

        // no-max softmax: P = exp2(S'), per-lane partial row-sum
        s16x4 pb[2][2];
        #pragma unroll
        for (int mi = 0; mi < 2; ++mi) {
            float rs = 0.0f;
            #pragma unroll
            for (int ni = 0; ni < 2; ++ni) {
                B4 pk;
                #pragma unroll
                for (int r = 0; r < 4; ++r) {
                    float pv = exp2_fast(pacc[mi][ni][r]);
                    rs += pv;
                    pk.b[r] = (__bf16)pv;
                }
                pb[mi][ni] = pk.s;
            }
            l_par[mi] += rs;
        }

        // O^T[d][q] += sum_t V^T[d][t] P^T[t][q]   (2 chunks of K=16)
        __builtin_amdgcn_s_setprio(1);
        #pragma unroll
        for (int c = 0; c < 2; ++c) {
            s16x4 vf[4];
            #pragma unroll
            for (int nd = 0; nd < 4; ++nd) {
                B4 vv;
                vv.b = *(const bf16x4*)&Vs[cur][16 * nd + l15][16 * c + 4 * g];
                vf[nd] = vv.s;
            }
            #pragma unroll
            for (int mi = 0; mi < 2; ++mi)
                #pragma unroll
                for (int nd = 0; nd < 4; ++nd)
                    acc_o[mi][nd] = MFMA16K16(vf[nd], pb[mi][c], acc_o[mi][nd]);
        }
        __builtin_amdgcn_s_setprio(0);
        cur ^= 1;
    }

    #pragma unroll
    for (int mi = 0; mi < 2; ++mi) {
        float l = l_par[mi];
        l += __shfl_xor(l, 16);
        l += __shfl_xor(l, 32);
        float rl = 1.0f / l;
        int q = qt * 64 + 32 * w + 16 * mi + l15;
        #pragma unroll
        for (int nd = 0; nd < 4; ++nd) {
            bf16x4 ov;
            #pragma unroll
            for (int r = 0; r < 4; ++r) ov[r] = (__bf16)(acc_o[mi][nd][r] * rl);
            *(bf16x4*)&Oh[(size_t)(bh * 1024 + q) * 64 + 16 * nd + 4 * g] = ov;
        }
    }
}

// ---------------- head mean (bf16 -> bf16, vectorized) ----------------
__global__ __launch_bounds__(256) void mean_kernel(
    const __bf16* __restrict__ Oh, __bf16* __restrict__ Om)
{
    int idx = blockIdx.x * 256 + threadIdx.x;
    int m = idx >> 3, d8 = (idx & 7) * 8;
    int b = m >> 10, q = m & 1023;
    const __bf16* src = Oh + (size_t)(b * 16) * 65536 + (size_t)q * 64 + d8;
    float s[8] = {};
    #pragma unroll
    for (int h = 0; h < 16; ++h) {
        bf16x8 v = *(const bf16x8*)&src[(size_t)h * 65536];
        #pragma unroll
        for (int j = 0; j < 8; ++j) s[j] += (float)v[j];
    }
    bf16x8 o;
    #pragma unroll
    for (int j = 0; j < 8; ++j) o[j] = (__bf16)(s[j] * 0.0625f);
    *(bf16x8*)&Om[(size_t)m * 64 + d8] = o;
}

// ---------------- output GEMM: [8192,64] x WoT[n][64] + bo -> f32 -----------
__global__ __launch_bounds__(256, 4) void out_gemm(
    const __bf16* __restrict__ Om, const __bf16* __restrict__ WoT,
    const float* __restrict__ bo, float* __restrict__ out)
{
    const int tid = threadIdx.x;
    const int lane = tid & 63, w = tid >> 6;
    const int wr = w >> 1, wc = w & 1;
    const int l15 = lane & 15, g = lane >> 4;
    const int m0 = blockIdx.x * 128, n0 = blockIdx.y * 128;

    f32x4 acc[4][4] = {};
    #pragma unroll
    for (int ks = 0; ks < 2; ++ks) {
        bf16x8 af[4], bfv[4];
        #pragma unroll
        for (int mi = 0; mi < 4; ++mi)
            af[mi] = *(const bf16x8*)&Om[(size_t)(m0 + 64 * wr + 16 * mi + l15) * 64 + 32 * ks + 8 * g];
        #pragma unroll
        for (int ni = 0; ni < 4; ++ni)
            bfv[ni] = *(const bf16x8*)&WoT[(size_t)(n0 + 64 * wc + 16 * ni + l15) * 64 + 32 * ks + 8 * g];
        #pragma unroll
        for (int mi = 0; mi < 4; ++mi)
            #pragma unroll
            for (int ni = 0; ni < 4; ++ni)
                acc[mi][ni] = MFMA16(af[mi], bfv[ni], acc[mi][ni]);
    }
    #pragma unroll
    for (int mi = 0; mi < 4; ++mi)
        #pragma unroll
        for (int ni = 0; ni < 4; ++ni) {
            int n = n0 + 64 * wc + 16 * ni + l15;
            float bn = bo[n];
            #pragma unroll
            for (int r = 0; r < 4; ++r) {
                int m = m0 + 64 * wr + 16 * mi + 4 * g + r;
                out[(size_t)m * 1024 + n] = acc[mi][ni][r] + bn;
            }
        }
}

extern "C" void kernel_launch(void* const* d_in, const int* in_sizes, int n_in,
                              void* d_out, int out_size, void* d_ws, size_t ws_size,
                              hipStream_t stream)
{
    const float* query = (const float*)d_in[0];
    const float* key_  = (const float*)d_in[1];
    const float* value = (const float*)d_in[2];
    const float* Wq = (const float*)d_in[3];
    const float* bq = (const float*)d_in[4];
    const float* Wk = (const float*)d_in[5];
    const float* bk = (const float*)d_in[6];
    const float* Wv = (const float*)d_in[7];
    const float* bv = (const float*)d_in[8];
    const float* Wo = (const float*)d_in[9];
    const float* bo = (const float*)d_in[10];
    float* out = (float*)d_out;

    char* p = (char*)d_ws;
    __bf16* Qbuf = (__bf16*)p; p += 8192ull * 1024 * 2;
    __bf16* Kbuf = (__bf16*)p; p += 8192ull * 1024 * 2;
    __bf16* VtB  = (__bf16*)p; p += 64ull * 8192 * 2;
    __bf16* WqT  = (__bf16*)p; p += 1024ull * 1024 * 2;
    __bf16* WkT  = (__bf16*)p; p += 1024ull * 1024 * 2;
    __bf16* WvT  = (__bf16*)p; p += 128ull * 1024 * 2;
    __bf16* WoT  = (__bf16*)p; p += 1024ull * 64 * 2;
    float*  bvP  = (float*)p;  p += 128 * 4;
    __bf16* Oh   = (__bf16*)p; p += 8ull * 16 * 1024 * 64 * 2;
    __bf16* Om   = (__bf16*)p; p += 8192ull * 64 * 2;

    pack_all<<<768, 256, 0, stream>>>(Wq, Wk, Wv, bv, Wo, WqT, WkT, WvT, bvP, WoT);
    proj_qk<<<dim3(64, 8, 2), 256, 0, stream>>>(query, key_, WqT, WkT, bq, bk, Qbuf, Kbuf);
    proj_v<<<128, 256, 0, stream>>>(value, WvT, bvP, VtB);
    attn_kernel<<<dim3(16, 128), 128, 0, stream>>>(Qbuf, Kbuf, VtB, Oh);
    mean_kernel<<<256, 256, 0, stream>>>(Oh, Om);
    out_gemm<<<dim3(64, 8), 256, 0, stream>>>(Om, WoT, bo, out);
}

// Round 21
// 140.583 us; speedup vs baseline: 2.4466x; 2.4466x over previous
//
#include <hip/hip_runtime.h>
#include <hip/hip_bf16.h>
#include <math.h>

typedef __attribute__((ext_vector_type(4))) float  f32x4;
typedef __attribute__((ext_vector_type(8))) __bf16 bf16x8;
typedef __attribute__((ext_vector_type(4))) __bf16 bf16x4;
typedef __attribute__((ext_vector_type(4))) short  s16x4;

#define SCL 0.18033688011111543f   // 0.125 * log2(e)
#define MFMA16(a, b, c)   __builtin_amdgcn_mfma_f32_16x16x32_bf16((a), (b), (c), 0, 0, 0)
#define MFMA16K16(a, b, c) __builtin_amdgcn_mfma_f32_16x16x16bf16_1k((a), (b), (c), 0, 0, 0)

union B4 { bf16x4 b; s16x4 s; };

__device__ __forceinline__ float exp2_fast(float x) {
    float r;
    asm("v_exp_f32 %0, %1" : "=v"(r) : "v"(x));
    return r;
}

// ---------------- combined pack: Wq/Wk transpose + WvT/WoT/bvP ---------------
__global__ __launch_bounds__(256) void pack_all(
    const float* __restrict__ Wq, const float* __restrict__ Wk,
    const float* __restrict__ Wv, const float* __restrict__ bv,
    const float* __restrict__ Wo,
    __bf16* __restrict__ WqT, __bf16* __restrict__ WkT,
    __bf16* __restrict__ WvT, float* __restrict__ bvP, __bf16* __restrict__ WoT)
{
    const int tid = threadIdx.x;
    if (blockIdx.x >= 256) {          // misc packs
        int idx = (blockIdx.x - 256) * 256 + tid;
        if (idx < 131072) {
            int n = idx >> 10, k = idx & 1023;
            WvT[idx] = (n < 64) ? (__bf16)Wv[k * 64 + n] : (__bf16)0.0f;
        }
        if (idx < 65536) {
            int n = idx >> 6, d = idx & 63;
            WoT[idx] = (__bf16)Wo[d * 1024 + n];
        }
        if (idx < 128) bvP[idx] = (idx < 64) ? bv[idx] : 0.0f;
        return;
    }
    __shared__ __bf16 T0[64][68];
    __shared__ __bf16 T1[64][68];
    const int h = blockIdx.x & 15, kt = blockIdx.x >> 4;   // 256 blocks
    const int kk = tid >> 2, cf = (tid & 3) * 16;
    const size_t base = (size_t)h * 65536 + (size_t)(kt * 64 + kk) * 64 + cf;
    #pragma unroll
    for (int j = 0; j < 4; ++j) {
        f32x4 v = *(const f32x4*)&Wq[base + 4 * j];
        f32x4 u = *(const f32x4*)&Wk[base + 4 * j];
        bf16x4 vb, ub;
        #pragma unroll
        for (int e = 0; e < 4; ++e) { vb[e] = (__bf16)v[e]; ub[e] = (__bf16)u[e]; }
        *(bf16x4*)&T0[kk][cf + 4 * j] = vb;
        *(bf16x4*)&T1[kk][cf + 4 * j] = ub;
    }
    __syncthreads();
    const int c = tid >> 2, k8 = (tid & 3) * 16;
    bf16x8 q0, q1, k0v, k1v;
    #pragma unroll
    for (int j = 0; j < 8; ++j) {
        q0[j] = T0[k8 + j][c];     q1[j] = T0[k8 + 8 + j][c];
        k0v[j] = T1[k8 + j][c];    k1v[j] = T1[k8 + 8 + j][c];
    }
    size_t dst = (size_t)(h * 64 + c) * 1024 + kt * 64 + k8;
    *(bf16x8*)&WqT[dst] = q0;  *(bf16x8*)&WqT[dst + 8] = q1;
    *(bf16x8*)&WkT[dst] = k0v; *(bf16x8*)&WkT[dst + 8] = k1v;
}

// ---------------- Q+K projection (fused via z): BM=128 BN=128 BK=64 ---------
// R5/R10-proven config: 256 thr, 2 blocks/CU, dbuf, fused f32->bf16 cvt.
__global__ __launch_bounds__(256, 2) void proj_qk(
    const float* __restrict__ Aq, const float* __restrict__ Ak,
    const __bf16* __restrict__ WqT, const __bf16* __restrict__ WkT,
    const float* __restrict__ bq, const float* __restrict__ bk,
    __bf16* __restrict__ Cq, __bf16* __restrict__ Ck)
{
    const int z = blockIdx.z;
    const float* A  = z ? Ak : Aq;
    const __bf16* Bt = z ? WkT : WqT;
    const float* bias = z ? bk : bq;
    __bf16* C = z ? Ck : Cq;
    const float oscale = z ? 1.0f : SCL;

    __shared__ __bf16 As[2][128][72];
    __shared__ __bf16 Bs[2][128][72];

    const int tid = threadIdx.x;
    const int lane = tid & 63, w = tid >> 6;
    const int wr = w >> 1, wc = w & 1;
    const int l15 = lane & 15, g = lane >> 4;
    const int m0 = blockIdx.x * 128, n0 = blockIdx.y * 128;
    const int arow = tid >> 4, acf = (tid & 15) * 4;
    const int brow = tid >> 3, bc8 = (tid & 7) * 8;

    f32x4 areg[8];
    bf16x8 breg[4];
    #pragma unroll
    for (int p = 0; p < 8; ++p)
        areg[p] = *(const f32x4*)&A[(size_t)(m0 + arow + 16 * p) * 1024 + acf];
    #pragma unroll
    for (int p = 0; p < 4; ++p)
        breg[p] = *(const bf16x8*)&Bt[(size_t)(n0 + brow + 32 * p) * 1024 + bc8];

    f32x4 acc[4][4] = {};
    int cur = 0;
    for (int k0 = 0; k0 < 1024; k0 += 64) {
        #pragma unroll
        for (int p = 0; p < 8; ++p) {
            bf16x4 c4;
            #pragma unroll
            for (int e = 0; e < 4; ++e) c4[e] = (__bf16)areg[p][e];
            *(bf16x4*)&As[cur][arow + 16 * p][acf] = c4;
        }
        #pragma unroll
        for (int p = 0; p < 4; ++p)
            *(bf16x8*)&Bs[cur][brow + 32 * p][bc8] = breg[p];
        if (k0 < 960) {
            #pragma unroll
            for (int p = 0; p < 8; ++p)
                areg[p] = *(const f32x4*)&A[(size_t)(m0 + arow + 16 * p) * 1024 + k0 + 64 + acf];
            #pragma unroll
            for (int p = 0; p < 4; ++p)
                breg[p] = *(const bf16x8*)&Bt[(size_t)(n0 + brow + 32 * p) * 1024 + k0 + 64 + bc8];
        }
        __syncthreads();
        __builtin_amdgcn_s_setprio(1);
        #pragma unroll
        for (int ks = 0; ks < 2; ++ks) {
            bf16x8 af[4], bfv[4];
            #pragma unroll
            for (int mi = 0; mi < 4; ++mi)
                af[mi] = *(const bf16x8*)&As[cur][64 * wr + 16 * mi + l15][32 * ks + 8 * g];
            #pragma unroll
            for (int ni = 0; ni < 4; ++ni)
                bfv[ni] = *(const bf16x8*)&Bs[cur][64 * wc + 16 * ni + l15][32 * ks + 8 * g];
            #pragma unroll
            for (int mi = 0; mi < 4; ++mi)
                #pragma unroll
                for (int ni = 0; ni < 4; ++ni)
                    acc[mi][ni] = MFMA16(af[mi], bfv[ni], acc[mi][ni]);
        }
        __builtin_amdgcn_s_setprio(0);
        cur ^= 1;
    }

    #pragma unroll
    for (int mi = 0; mi < 4; ++mi)
        #pragma unroll
        for (int ni = 0; ni < 4; ++ni) {
            int n = n0 + 64 * wc + 16 * ni + l15;
            float bn = bias[n];
            #pragma unroll
            for (int r = 0; r < 4; ++r) {
                int m = m0 + 64 * wr + 16 * mi + 4 * g + r;
                C[(size_t)m * 1024 + n] = (__bf16)((acc[mi][ni][r] + bn) * oscale);
            }
        }
}

// ---------------- V projection: BM=64, BN=64, transposed store (V^T) --------
__global__ __launch_bounds__(256, 2) void proj_v(
    const float* __restrict__ A, const __bf16* __restrict__ Bt,
    const float* __restrict__ bias, __bf16* __restrict__ C)
{
    __shared__ __bf16 As[2][64][72];
    __shared__ __bf16 Bs[2][64][72];

    const int tid = threadIdx.x;
    const int lane = tid & 63, w = tid >> 6;
    const int wr = w >> 1, wc = w & 1;
    const int l15 = lane & 15, g = lane >> 4;
    const int m0 = blockIdx.x * 64;
    const int arow = tid >> 2, acf = (tid & 3) * 16;
    const int bcf = (tid & 3) * 16;

    f32x4 areg[4];
    bf16x8 breg[2];
    #pragma unroll
    for (int j = 0; j < 4; ++j)
        areg[j] = *(const f32x4*)&A[(size_t)(m0 + arow) * 1024 + acf + 4 * j];
    #pragma unroll
    for (int j = 0; j < 2; ++j)
        breg[j] = *(const bf16x8*)&Bt[(size_t)arow * 1024 + bcf + 8 * j];

    f32x4 acc[2][2] = {};
    int cur = 0;
    for (int k0 = 0; k0 < 1024; k0 += 64) {
        #pragma unroll
        for (int j = 0; j < 4; ++j) {
            bf16x4 c4;
            #pragma unroll
            for (int e = 0; e < 4; ++e) c4[e] = (__bf16)areg[j][e];
            *(bf16x4*)&As[cur][arow][acf + 4 * j] = c4;
        }
        #pragma unroll
        for (int j = 0; j < 2; ++j)
            *(bf16x8*)&Bs[cur][arow][bcf + 8 * j] = breg[j];
        if (k0 < 960) {
            #pragma unroll
            for (int j = 0; j < 4; ++j)
                areg[j] = *(const f32x4*)&A[(size_t)(m0 + arow) * 1024 + k0 + 64 + acf + 4 * j];
            #pragma unroll
            for (int j = 0; j < 2; ++j)
                breg[j] = *(const bf16x8*)&Bt[(size_t)arow * 1024 + k0 + 64 + bcf + 8 * j];
        }
        __syncthreads();
        #pragma unroll
        for (int ks = 0; ks < 2; ++ks) {
            bf16x8 af[2], bfv[2];
            #pragma unroll
            for (int mi = 0; mi < 2; ++mi)
                af[mi] = *(const bf16x8*)&As[cur][32 * wr + 16 * mi + l15][32 * ks + 8 * g];
            #pragma unroll
            for (int ni = 0; ni < 2; ++ni)
                bfv[ni] = *(const bf16x8*)&Bs[cur][32 * wc + 16 * ni + l15][32 * ks + 8 * g];
            #pragma unroll
            for (int mi = 0; mi < 2; ++mi)
                #pragma unroll
                for (int ni = 0; ni < 2; ++ni)
                    acc[mi][ni] = MFMA16(af[mi], bfv[ni], acc[mi][ni]);
        }
        __syncthreads();
        cur ^= 1;
    }

    #pragma unroll
    for (int mi = 0; mi < 2; ++mi)
        #pragma unroll
        for (int ni = 0; ni < 2; ++ni) {
            int n = 32 * wc + 16 * ni + l15;
            float bn = bias[n];
            #pragma unroll
            for (int r = 0; r < 4; ++r) {
                int m = m0 + 32 * wr + 16 * mi + 4 * g + r;
                C[(size_t)n * 8192 + m] = (__bf16)(acc[mi][ni][r] + bn);   // V^T
            }
        }
}

// ---------------- fused attention: R8-exact (LDS V stride 44), v_exp_f32 ----
__global__ __launch_bounds__(128, 4) void attn_kernel(
    const __bf16* __restrict__ Qb, const __bf16* __restrict__ Kb,
    const __bf16* __restrict__ Vt, __bf16* __restrict__ Oh)
{
    __shared__ __bf16 Ks[2][32][68];     // 34-dword stride
    __shared__ __bf16 Vs[2][64][44];     // 22-dword stride (proven best, R8)

    const int qt = blockIdx.x, bh = blockIdx.y;
    const int b = bh >> 4, h = bh & 15;
    const int tid = threadIdx.x;
    const int lane = tid & 63, w = tid >> 6;       // 2 waves
    const int l15 = lane & 15, g = lane >> 4;
    const int s0 = b * 1024 + qt * 64;

    const int krow = tid >> 2, kc = (tid & 3) * 16;   // K: 32 rows, 4 thr/row
    const int vrow = tid >> 1, vc = (tid & 1) * 16;   // V: 64 rows, 2 thr/row

    // Q fragments (wave owns 32 q-rows); Q pre-scaled by 0.125*log2(e)
    bf16x8 qf[2][2];
    #pragma unroll
    for (int mi = 0; mi < 2; ++mi)
        #pragma unroll
        for (int ks = 0; ks < 2; ++ks)
            qf[mi][ks] = *(const bf16x8*)
                &Qb[(size_t)(s0 + 32 * w + 16 * mi + l15) * 1024 + h * 64 + 32 * ks + 8 * g];

    const __bf16* Kbase = Kb + (size_t)(b * 1024) * 1024 + h * 64;
    const __bf16* Vbase = Vt + (size_t)b * 1024;

    bf16x8 kreg[2], vreg[2];
    #pragma unroll
    for (int j = 0; j < 2; ++j) {
        kreg[j] = *(const bf16x8*)&Kbase[(size_t)krow * 1024 + kc + 8 * j];
        vreg[j] = *(const bf16x8*)&Vbase[(size_t)vrow * 8192 + vc + 8 * j];
    }

    f32x4 acc_o[2][4] = {};
    float l_par[2] = {0.0f, 0.0f};

    int cur = 0;
    for (int it = 0; it < 32; ++it) {
        *(bf16x8*)&Ks[cur][krow][kc]     = kreg[0];
        *(bf16x8*)&Ks[cur][krow][kc + 8] = kreg[1];
        *(bf16x8*)&Vs[cur][vrow][vc]     = vreg[0];
        *(bf16x8*)&Vs[cur][vrow][vc + 8] = vreg[1];
        if (it < 31) {
            int t1 = (it + 1) * 32;
            #pragma unroll
            for (int j = 0; j < 2; ++j) {
                kreg[j] = *(const bf16x8*)&Kbase[(size_t)(t1 + krow) * 1024 + kc + 8 * j];
                vreg[j] = *(const bf16x8*)&Vbase[(size_t)vrow * 8192 + t1 + vc + 8 * j];
            }
        }
        __syncthreads();

        // S^T[t][q] = sum_d K[t][d] Q[q][d]   (already log2-scaled via Q)
        f32x4 pacc[2][2] = {};
        __builtin_amdgcn_s_setprio(1);
        #pragma unroll
        for (int ks = 0; ks < 2; ++ks) {
            bf16x8 kf[2];
            #pragma unroll
            for (int ni = 0; ni < 2; ++ni)
                kf[ni] = *(const bf16x8*)&Ks[cur][16 * ni + l15][32 * ks + 8 * g];
            #pragma unroll
            for (int mi = 0; mi < 2; ++mi)
                #pragma unroll
                for (int ni = 0; ni < 2; ++ni)
                    pacc[mi][ni] = MFMA16(kf[ni], qf[mi][ks], pacc[mi][ni]);
        }
        __builtin_amdgcn_s_setprio(0);

        // no-max softmax: P = exp2(S'), per-lane partial row-sum
        s16x4 pb[2][2];
        #pragma unroll
        for (int mi = 0; mi < 2; ++mi) {
            float rs = 0.0f;
            #pragma unroll
            for (int ni = 0; ni < 2; ++ni) {
                B4 pk;
                #pragma unroll
                for (int r = 0; r < 4; ++r) {
                    float pv = exp2_fast(pacc[mi][ni][r]);
                    rs += pv;
                    pk.b[r] = (__bf16)pv;
                }
                pb[mi][ni] = pk.s;
            }
            l_par[mi] += rs;
        }

        // O^T[d][q] += sum_t V^T[d][t] P^T[t][q]   (2 chunks of K=16)
        __builtin_amdgcn_s_setprio(1);
        #pragma unroll
        for (int c = 0; c < 2; ++c) {
            s16x4 vf[4];
            #pragma unroll
            for (int nd = 0; nd < 4; ++nd) {
                B4 vv;
                vv.b = *(const bf16x4*)&Vs[cur][16 * nd + l15][16 * c + 4 * g];
                vf[nd] = vv.s;
            }
            #pragma unroll
            for (int mi = 0; mi < 2; ++mi)
                #pragma unroll
                for (int nd = 0; nd < 4; ++nd)
                    acc_o[mi][nd] = MFMA16K16(vf[nd], pb[mi][c], acc_o[mi][nd]);
        }
        __builtin_amdgcn_s_setprio(0);
        cur ^= 1;
    }

    #pragma unroll
    for (int mi = 0; mi < 2; ++mi) {
        float l = l_par[mi];
        l += __shfl_xor(l, 16);
        l += __shfl_xor(l, 32);
        float rl = 1.0f / l;
        int q = qt * 64 + 32 * w + 16 * mi + l15;
        #pragma unroll
        for (int nd = 0; nd < 4; ++nd) {
            bf16x4 ov;
            #pragma unroll
            for (int r = 0; r < 4; ++r) ov[r] = (__bf16)(acc_o[mi][nd][r] * rl);
            *(bf16x4*)&Oh[(size_t)(bh * 1024 + q) * 64 + 16 * nd + 4 * g] = ov;
        }
    }
}

// ---------------- head mean (bf16 -> bf16, vectorized) ----------------
__global__ __launch_bounds__(256) void mean_kernel(
    const __bf16* __restrict__ Oh, __bf16* __restrict__ Om)
{
    int idx = blockIdx.x * 256 + threadIdx.x;
    int m = idx >> 3, d8 = (idx & 7) * 8;
    int b = m >> 10, q = m & 1023;
    const __bf16* src = Oh + (size_t)(b * 16) * 65536 + (size_t)q * 64 + d8;
    float s[8] = {};
    #pragma unroll
    for (int h = 0; h < 16; ++h) {
        bf16x8 v = *(const bf16x8*)&src[(size_t)h * 65536];
        #pragma unroll
        for (int j = 0; j < 8; ++j) s[j] += (float)v[j];
    }
    bf16x8 o;
    #pragma unroll
    for (int j = 0; j < 8; ++j) o[j] = (__bf16)(s[j] * 0.0625f);
    *(bf16x8*)&Om[(size_t)m * 64 + d8] = o;
}

// ---------------- output GEMM: [8192,64] x WoT[n][64] + bo -> f32 -----------
__global__ __launch_bounds__(256, 4) void out_gemm(
    const __bf16* __restrict__ Om, const __bf16* __restrict__ WoT,
    const float* __restrict__ bo, float* __restrict__ out)
{
    const int tid = threadIdx.x;
    const int lane = tid & 63, w = tid >> 6;
    const int wr = w >> 1, wc = w & 1;
    const int l15 = lane & 15, g = lane >> 4;
    const int m0 = blockIdx.x * 128, n0 = blockIdx.y * 128;

    f32x4 acc[4][4] = {};
    #pragma unroll
    for (int ks = 0; ks < 2; ++ks) {
        bf16x8 af[4], bfv[4];
        #pragma unroll
        for (int mi = 0; mi < 4; ++mi)
            af[mi] = *(const bf16x8*)&Om[(size_t)(m0 + 64 * wr + 16 * mi + l15) * 64 + 32 * ks + 8 * g];
        #pragma unroll
        for (int ni = 0; ni < 4; ++ni)
            bfv[ni] = *(const bf16x8*)&WoT[(size_t)(n0 + 64 * wc + 16 * ni + l15) * 64 + 32 * ks + 8 * g];
        #pragma unroll
        for (int mi = 0; mi < 4; ++mi)
            #pragma unroll
            for (int ni = 0; ni < 4; ++ni)
                acc[mi][ni] = MFMA16(af[mi], bfv[ni], acc[mi][ni]);
    }
    #pragma unroll
    for (int mi = 0; mi < 4; ++mi)
        #pragma unroll
        for (int ni = 0; ni < 4; ++ni) {
            int n = n0 + 64 * wc + 16 * ni + l15;
            float bn = bo[n];
            #pragma unroll
            for (int r = 0; r < 4; ++r) {
                int m = m0 + 64 * wr + 16 * mi + 4 * g + r;
                out[(size_t)m * 1024 + n] = acc[mi][ni][r] + bn;
            }
        }
}

extern "C" void kernel_launch(void* const* d_in, const int* in_sizes, int n_in,
                              void* d_out, int out_size, void* d_ws, size_t ws_size,
                              hipStream_t stream)
{
    const float* query = (const float*)d_in[0];
    const float* key_  = (const float*)d_in[1];
    const float* value = (const float*)d_in[2];
    const float* Wq = (const float*)d_in[3];
    const float* bq = (const float*)d_in[4];
    const float* Wk = (const float*)d_in[5];
    const float* bk = (const float*)d_in[6];
    const float* Wv = (const float*)d_in[7];
    const float* bv = (const float*)d_in[8];
    const float* Wo = (const float*)d_in[9];
    const float* bo = (const float*)d_in[10];
    float* out = (float*)d_out;

    char* p = (char*)d_ws;
    __bf16* Qbuf = (__bf16*)p; p += 8192ull * 1024 * 2;
    __bf16* Kbuf = (__bf16*)p; p += 8192ull * 1024 * 2;
    __bf16* VtB  = (__bf16*)p; p += 64ull * 8192 * 2;
    __bf16* WqT  = (__bf16*)p; p += 1024ull * 1024 * 2;
    __bf16* WkT  = (__bf16*)p; p += 1024ull * 1024 * 2;
    __bf16* WvT  = (__bf16*)p; p += 128ull * 1024 * 2;
    __bf16* WoT  = (__bf16*)p; p += 1024ull * 64 * 2;
    float*  bvP  = (float*)p;  p += 128 * 4;
    __bf16* Oh   = (__bf16*)p; p += 8ull * 16 * 1024 * 64 * 2;
    __bf16* Om   = (__bf16*)p; p += 8192ull * 64 * 2;

    pack_all<<<768, 256, 0, stream>>>(Wq, Wk, Wv, bv, Wo, WqT, WkT, WvT, bvP, WoT);
    proj_qk<<<dim3(64, 8, 2), 256, 0, stream>>>(query, key_, WqT, WkT, bq, bk, Qbuf, Kbuf);
    proj_v<<<128, 256, 0, stream>>>(value, WvT, bvP, VtB);
    attn_kernel<<<dim3(16, 128), 128, 0, stream>>>(Qbuf, Kbuf, VtB, Oh);
    mean_kernel<<<256, 256, 0, stream>>>(Oh, Om);
    out_gemm<<<dim3(64, 8), 256, 0, stream>>>(Om, WoT, bo, out);
}

// Round 22
// 140.228 us; speedup vs baseline: 2.4528x; 1.0025x over previous
//
#include <hip/hip_runtime.h>
#include <hip/hip_bf16.h>
#include <math.h>

typedef __attribute__((ext_vector_type(4))) float  f32x4;
typedef __attribute__((ext_vector_type(8))) __bf16 bf16x8;
typedef __attribute__((ext_vector_type(4))) __bf16 bf16x4;
typedef __attribute__((ext_vector_type(4))) short  s16x4;

#define SCL 0.18033688011111543f   // 0.125 * log2(e)
#define MFMA16(a, b, c)   __builtin_amdgcn_mfma_f32_16x16x32_bf16((a), (b), (c), 0, 0, 0)
#define MFMA16K16(a, b, c) __builtin_amdgcn_mfma_f32_16x16x16bf16_1k((a), (b), (c), 0, 0, 0)

union B4 { bf16x4 b; s16x4 s; };

__device__ __forceinline__ float exp2_fast(float x) {
    float r;
    asm("v_exp_f32 %0, %1" : "=v"(r) : "v"(x));
    return r;
}

// ---------------- combined pack: Wq/Wk transpose + WvT/WoT/bvP ---------------
__global__ __launch_bounds__(256) void pack_all(
    const float* __restrict__ Wq, const float* __restrict__ Wk,
    const float* __restrict__ Wv, const float* __restrict__ bv,
    const float* __restrict__ Wo,
    __bf16* __restrict__ WqT, __bf16* __restrict__ WkT,
    __bf16* __restrict__ WvT, float* __restrict__ bvP, __bf16* __restrict__ WoT)
{
    const int tid = threadIdx.x;
    if (blockIdx.x >= 256) {          // misc packs
        int idx = (blockIdx.x - 256) * 256 + tid;
        if (idx < 131072) {
            int n = idx >> 10, k = idx & 1023;
            WvT[idx] = (n < 64) ? (__bf16)Wv[k * 64 + n] : (__bf16)0.0f;
        }
        if (idx < 65536) {
            int n = idx >> 6, d = idx & 63;
            WoT[idx] = (__bf16)Wo[d * 1024 + n];
        }
        if (idx < 128) bvP[idx] = (idx < 64) ? bv[idx] : 0.0f;
        return;
    }
    __shared__ __bf16 T0[64][68];
    __shared__ __bf16 T1[64][68];
    const int h = blockIdx.x & 15, kt = blockIdx.x >> 4;   // 256 blocks
    const int kk = tid >> 2, cf = (tid & 3) * 16;
    const size_t base = (size_t)h * 65536 + (size_t)(kt * 64 + kk) * 64 + cf;
    #pragma unroll
    for (int j = 0; j < 4; ++j) {
        f32x4 v = *(const f32x4*)&Wq[base + 4 * j];
        f32x4 u = *(const f32x4*)&Wk[base + 4 * j];
        bf16x4 vb, ub;
        #pragma unroll
        for (int e = 0; e < 4; ++e) { vb[e] = (__bf16)v[e]; ub[e] = (__bf16)u[e]; }
        *(bf16x4*)&T0[kk][cf + 4 * j] = vb;
        *(bf16x4*)&T1[kk][cf + 4 * j] = ub;
    }
    __syncthreads();
    const int c = tid >> 2, k8 = (tid & 3) * 16;
    bf16x8 q0, q1, k0v, k1v;
    #pragma unroll
    for (int j = 0; j < 8; ++j) {
        q0[j] = T0[k8 + j][c];     q1[j] = T0[k8 + 8 + j][c];
        k0v[j] = T1[k8 + j][c];    k1v[j] = T1[k8 + 8 + j][c];
    }
    size_t dst = (size_t)(h * 64 + c) * 1024 + kt * 64 + k8;
    *(bf16x8*)&WqT[dst] = q0;  *(bf16x8*)&WqT[dst + 8] = q1;
    *(bf16x8*)&WkT[dst] = k0v; *(bf16x8*)&WkT[dst + 8] = k1v;
}

// ---------------- Q+K projection: single-buffer BK=64, bound (256,2) --------
// R20 structure (LDS 36.9KB -> 4 blocks/CU) with the dbuf-proven launch bound
// so the allocator keeps the natural ~100-VGPR live set (R20's (256,4) bound
// squeezed VGPR to 64 and spilled the prefetch regs -> 627MB scratch traffic).
__global__ __launch_bounds__(256, 2) void proj_qk(
    const float* __restrict__ Aq, const float* __restrict__ Ak,
    const __bf16* __restrict__ WqT, const __bf16* __restrict__ WkT,
    const float* __restrict__ bq, const float* __restrict__ bk,
    __bf16* __restrict__ Cq, __bf16* __restrict__ Ck)
{
    const int z = blockIdx.z;
    const float* A  = z ? Ak : Aq;
    const __bf16* Bt = z ? WkT : WqT;
    const float* bias = z ? bk : bq;
    __bf16* C = z ? Ck : Cq;
    const float oscale = z ? 1.0f : SCL;

    __shared__ __bf16 As[128][72];
    __shared__ __bf16 Bs[128][72];

    const int tid = threadIdx.x;
    const int lane = tid & 63, w = tid >> 6;
    const int wr = w >> 1, wc = w & 1;
    const int l15 = lane & 15, g = lane >> 4;
    const int m0 = blockIdx.x * 128, n0 = blockIdx.y * 128;
    const int arow = tid >> 4, acf = (tid & 15) * 4;
    const int brow = tid >> 3, bc8 = (tid & 7) * 8;

    f32x4 areg[8];
    bf16x8 breg[4];
    #pragma unroll
    for (int p = 0; p < 8; ++p)
        areg[p] = *(const f32x4*)&A[(size_t)(m0 + arow + 16 * p) * 1024 + acf];
    #pragma unroll
    for (int p = 0; p < 4; ++p)
        breg[p] = *(const bf16x8*)&Bt[(size_t)(n0 + brow + 32 * p) * 1024 + bc8];

    f32x4 acc[4][4] = {};
    for (int k0 = 0; k0 < 1024; k0 += 64) {
        #pragma unroll
        for (int p = 0; p < 8; ++p) {
            bf16x4 c4;
            #pragma unroll
            for (int e = 0; e < 4; ++e) c4[e] = (__bf16)areg[p][e];
            *(bf16x4*)&As[arow + 16 * p][acf] = c4;
        }
        #pragma unroll
        for (int p = 0; p < 4; ++p)
            *(bf16x8*)&Bs[brow + 32 * p][bc8] = breg[p];
        if (k0 < 960) {
            #pragma unroll
            for (int p = 0; p < 8; ++p)
                areg[p] = *(const f32x4*)&A[(size_t)(m0 + arow + 16 * p) * 1024 + k0 + 64 + acf];
            #pragma unroll
            for (int p = 0; p < 4; ++p)
                breg[p] = *(const bf16x8*)&Bt[(size_t)(n0 + brow + 32 * p) * 1024 + k0 + 64 + bc8];
        }
        __syncthreads();
        __builtin_amdgcn_s_setprio(1);
        #pragma unroll
        for (int ks = 0; ks < 2; ++ks) {
            bf16x8 af[4], bfv[4];
            #pragma unroll
            for (int mi = 0; mi < 4; ++mi)
                af[mi] = *(const bf16x8*)&As[64 * wr + 16 * mi + l15][32 * ks + 8 * g];
            #pragma unroll
            for (int ni = 0; ni < 4; ++ni)
                bfv[ni] = *(const bf16x8*)&Bs[64 * wc + 16 * ni + l15][32 * ks + 8 * g];
            #pragma unroll
            for (int mi = 0; mi < 4; ++mi)
                #pragma unroll
                for (int ni = 0; ni < 4; ++ni)
                    acc[mi][ni] = MFMA16(af[mi], bfv[ni], acc[mi][ni]);
        }
        __builtin_amdgcn_s_setprio(0);
        __syncthreads();   // protect LDS before next-iter overwrite
    }

    #pragma unroll
    for (int mi = 0; mi < 4; ++mi)
        #pragma unroll
        for (int ni = 0; ni < 4; ++ni) {
            int n = n0 + 64 * wc + 16 * ni + l15;
            float bn = bias[n];
            #pragma unroll
            for (int r = 0; r < 4; ++r) {
                int m = m0 + 64 * wr + 16 * mi + 4 * g + r;
                C[(size_t)m * 1024 + n] = (__bf16)((acc[mi][ni][r] + bn) * oscale);
            }
        }
}

// ---------------- V projection: BM=64, BN=64, transposed store (V^T) --------
__global__ __launch_bounds__(256, 2) void proj_v(
    const float* __restrict__ A, const __bf16* __restrict__ Bt,
    const float* __restrict__ bias, __bf16* __restrict__ C)
{
    __shared__ __bf16 As[2][64][72];
    __shared__ __bf16 Bs[2][64][72];

    const int tid = threadIdx.x;
    const int lane = tid & 63, w = tid >> 6;
    const int wr = w >> 1, wc = w & 1;
    const int l15 = lane & 15, g = lane >> 4;
    const int m0 = blockIdx.x * 64;
    const int arow = tid >> 2, acf = (tid & 3) * 16;
    const int bcf = (tid & 3) * 16;

    f32x4 areg[4];
    bf16x8 breg[2];
    #pragma unroll
    for (int j = 0; j < 4; ++j)
        areg[j] = *(const f32x4*)&A[(size_t)(m0 + arow) * 1024 + acf + 4 * j];
    #pragma unroll
    for (int j = 0; j < 2; ++j)
        breg[j] = *(const bf16x8*)&Bt[(size_t)arow * 1024 + bcf + 8 * j];

    f32x4 acc[2][2] = {};
    int cur = 0;
    for (int k0 = 0; k0 < 1024; k0 += 64) {
        #pragma unroll
        for (int j = 0; j < 4; ++j) {
            bf16x4 c4;
            #pragma unroll
            for (int e = 0; e < 4; ++e) c4[e] = (__bf16)areg[j][e];
            *(bf16x4*)&As[cur][arow][acf + 4 * j] = c4;
        }
        #pragma unroll
        for (int j = 0; j < 2; ++j)
            *(bf16x8*)&Bs[cur][arow][bcf + 8 * j] = breg[j];
        if (k0 < 960) {
            #pragma unroll
            for (int j = 0; j < 4; ++j)
                areg[j] = *(const f32x4*)&A[(size_t)(m0 + arow) * 1024 + k0 + 64 + acf + 4 * j];
            #pragma unroll
            for (int j = 0; j < 2; ++j)
                breg[j] = *(const bf16x8*)&Bt[(size_t)arow * 1024 + k0 + 64 + bcf + 8 * j];
        }
        __syncthreads();
        #pragma unroll
        for (int ks = 0; ks < 2; ++ks) {
            bf16x8 af[2], bfv[2];
            #pragma unroll
            for (int mi = 0; mi < 2; ++mi)
                af[mi] = *(const bf16x8*)&As[cur][32 * wr + 16 * mi + l15][32 * ks + 8 * g];
            #pragma unroll
            for (int ni = 0; ni < 2; ++ni)
                bfv[ni] = *(const bf16x8*)&Bs[cur][32 * wc + 16 * ni + l15][32 * ks + 8 * g];
            #pragma unroll
            for (int mi = 0; mi < 2; ++mi)
                #pragma unroll
                for (int ni = 0; ni < 2; ++ni)
                    acc[mi][ni] = MFMA16(af[mi], bfv[ni], acc[mi][ni]);
        }
        __syncthreads();
        cur ^= 1;
    }

    #pragma unroll
    for (int mi = 0; mi < 2; ++mi)
        #pragma unroll
        for (int ni = 0; ni < 2; ++ni) {
            int n = 32 * wc + 16 * ni + l15;
            float bn = bias[n];
            #pragma unroll
            for (int r = 0; r < 4; ++r) {
                int m = m0 + 32 * wr + 16 * mi + 4 * g + r;
                C[(size_t)n * 8192 + m] = (__bf16)(acc[mi][ni][r] + bn);   // V^T
            }
        }
}

// ---------------- fused attention: R8-exact (LDS V stride 44), v_exp_f32 ----
__global__ __launch_bounds__(128, 4) void attn_kernel(
    const __bf16* __restrict__ Qb, const __bf16* __restrict__ Kb,
    const __bf16* __restrict__ Vt, __bf16* __restrict__ Oh)
{
    __shared__ __bf16 Ks[2][32][68];     // 34-dword stride
    __shared__ __bf16 Vs[2][64][44];     // 22-dword stride (proven best, R8)

    const int qt = blockIdx.x, bh = blockIdx.y;
    const int b = bh >> 4, h = bh & 15;
    const int tid = threadIdx.x;
    const int lane = tid & 63, w = tid >> 6;       // 2 waves
    const int l15 = lane & 15, g = lane >> 4;
    const int s0 = b * 1024 + qt * 64;

    const int krow = tid >> 2, kc = (tid & 3) * 16;   // K: 32 rows, 4 thr/row
    const int vrow = tid >> 1, vc = (tid & 1) * 16;   // V: 64 rows, 2 thr/row

    // Q fragments (wave owns 32 q-rows); Q pre-scaled by 0.125*log2(e)
    bf16x8 qf[2][2];
    #pragma unroll
    for (int mi = 0; mi < 2; ++mi)
        #pragma unroll
        for (int ks = 0; ks < 2; ++ks)
            qf[mi][ks] = *(const bf16x8*)
                &Qb[(size_t)(s0 + 32 * w + 16 * mi + l15) * 1024 + h * 64 + 32 * ks + 8 * g];

    const __bf16* Kbase = Kb + (size_t)(b * 1024) * 1024 + h * 64;
    const __bf16* Vbase = Vt + (size_t)b * 1024;

    bf16x8 kreg[2], vreg[2];
    #pragma unroll
    for (int j = 0; j < 2; ++j) {
        kreg[j] = *(const bf16x8*)&Kbase[(size_t)krow * 1024 + kc + 8 * j];
        vreg[j] = *(const bf16x8*)&Vbase[(size_t)vrow * 8192 + vc + 8 * j];
    }

    f32x4 acc_o[2][4] = {};
    float l_par[2] = {0.0f, 0.0f};

    int cur = 0;
    for (int it = 0; it < 32; ++it) {
        *(bf16x8*)&Ks[cur][krow][kc]     = kreg[0];
        *(bf16x8*)&Ks[cur][krow][kc + 8] = kreg[1];
        *(bf16x8*)&Vs[cur][vrow][vc]     = vreg[0];
        *(bf16x8*)&Vs[cur][vrow][vc + 8] = vreg[1];
        if (it < 31) {
            int t1 = (it + 1) * 32;
            #pragma unroll
            for (int j = 0; j < 2; ++j) {
                kreg[j] = *(const bf16x8*)&Kbase[(size_t)(t1 + krow) * 1024 + kc + 8 * j];
                vreg[j] = *(const bf16x8*)&Vbase[(size_t)vrow * 8192 + t1 + vc + 8 * j];
            }
        }
        __syncthreads();

        // S^T[t][q] = sum_d K[t][d] Q[q][d]   (already log2-scaled via Q)
        f32x4 pacc[2][2] = {};
        __builtin_amdgcn_s_setprio(1);
        #pragma unroll
        for (int ks = 0; ks < 2; ++ks) {
            bf16x8 kf[2];
            #pragma unroll
            for (int ni = 0; ni < 2; ++ni)
                kf[ni] = *(const bf16x8*)&Ks[cur][16 * ni + l15][32 * ks + 8 * g];
            #pragma unroll
            for (int mi = 0; mi < 2; ++mi)
                #pragma unroll
                for (int ni = 0; ni < 2; ++ni)
                    pacc[mi][ni] = MFMA16(kf[ni], qf[mi][ks], pacc[mi][ni]);
        }
        __builtin_amdgcn_s_setprio(0);

        // no-max softmax: P = exp2(S'), per-lane partial row-sum
        s16x4 pb[2][2];
        #pragma unroll
        for (int mi = 0; mi < 2; ++mi) {
            float rs = 0.0f;
            #pragma unroll
            for (int ni = 0; ni < 2; ++ni) {
                B4 pk;
                #pragma unroll
                for (int r = 0; r < 4; ++r) {
                    float pv = exp2_fast(pacc[mi][ni][r]);
                    rs += pv;
                    pk.b[r] = (__bf16)pv;
                }
                pb[mi][ni] = pk.s;
            }
            l_par[mi] += rs;
        }

        // O^T[d][q] += sum_t V^T[d][t] P^T[t][q]   (2 chunks of K=16)
        __builtin_amdgcn_s_setprio(1);
        #pragma unroll
        for (int c = 0; c < 2; ++c) {
            s16x4 vf[4];
            #pragma unroll
            for (int nd = 0; nd < 4; ++nd) {
                B4 vv;
                vv.b = *(const bf16x4*)&Vs[cur][16 * nd + l15][16 * c + 4 * g];
                vf[nd] = vv.s;
            }
            #pragma unroll
            for (int mi = 0; mi < 2; ++mi)
                #pragma unroll
                for (int nd = 0; nd < 4; ++nd)
                    acc_o[mi][nd] = MFMA16K16(vf[nd], pb[mi][c], acc_o[mi][nd]);
        }
        __builtin_amdgcn_s_setprio(0);
        cur ^= 1;
    }

    #pragma unroll
    for (int mi = 0; mi < 2; ++mi) {
        float l = l_par[mi];
        l += __shfl_xor(l, 16);
        l += __shfl_xor(l, 32);
        float rl = 1.0f / l;
        int q = qt * 64 + 32 * w + 16 * mi + l15;
        #pragma unroll
        for (int nd = 0; nd < 4; ++nd) {
            bf16x4 ov;
            #pragma unroll
            for (int r = 0; r < 4; ++r) ov[r] = (__bf16)(acc_o[mi][nd][r] * rl);
            *(bf16x4*)&Oh[(size_t)(bh * 1024 + q) * 64 + 16 * nd + 4 * g] = ov;
        }
    }
}

// ---------------- head mean (bf16 -> bf16, vectorized) ----------------
__global__ __launch_bounds__(256) void mean_kernel(
    const __bf16* __restrict__ Oh, __bf16* __restrict__ Om)
{
    int idx = blockIdx.x * 256 + threadIdx.x;
    int m = idx >> 3, d8 = (idx & 7) * 8;
    int b = m >> 10, q = m & 1023;
    const __bf16* src = Oh + (size_t)(b * 16) * 65536 + (size_t)q * 64 + d8;
    float s[8] = {};
    #pragma unroll
    for (int h = 0; h < 16; ++h) {
        bf16x8 v = *(const bf16x8*)&src[(size_t)h * 65536];
        #pragma unroll
        for (int j = 0; j < 8; ++j) s[j] += (float)v[j];
    }
    bf16x8 o;
    #pragma unroll
    for (int j = 0; j < 8; ++j) o[j] = (__bf16)(s[j] * 0.0625f);
    *(bf16x8*)&Om[(size_t)m * 64 + d8] = o;
}

// ---------------- output GEMM: [8192,64] x WoT[n][64] + bo -> f32 -----------
__global__ __launch_bounds__(256, 4) void out_gemm(
    const __bf16* __restrict__ Om, const __bf16* __restrict__ WoT,
    const float* __restrict__ bo, float* __restrict__ out)
{
    const int tid = threadIdx.x;
    const int lane = tid & 63, w = tid >> 6;
    const int wr = w >> 1, wc = w & 1;
    const int l15 = lane & 15, g = lane >> 4;
    const int m0 = blockIdx.x * 128, n0 = blockIdx.y * 128;

    f32x4 acc[4][4] = {};
    #pragma unroll
    for (int ks = 0; ks < 2; ++ks) {
        bf16x8 af[4], bfv[4];
        #pragma unroll
        for (int mi = 0; mi < 4; ++mi)
            af[mi] = *(const bf16x8*)&Om[(size_t)(m0 + 64 * wr + 16 * mi + l15) * 64 + 32 * ks + 8 * g];
        #pragma unroll
        for (int ni = 0; ni < 4; ++ni)
            bfv[ni] = *(const bf16x8*)&WoT[(size_t)(n0 + 64 * wc + 16 * ni + l15) * 64 + 32 * ks + 8 * g];
        #pragma unroll
        for (int mi = 0; mi < 4; ++mi)
            #pragma unroll
            for (int ni = 0; ni < 4; ++ni)
                acc[mi][ni] = MFMA16(af[mi], bfv[ni], acc[mi][ni]);
    }
    #pragma unroll
    for (int mi = 0; mi < 4; ++mi)
        #pragma unroll
        for (int ni = 0; ni < 4; ++ni) {
            int n = n0 + 64 * wc + 16 * ni + l15;
            float bn = bo[n];
            #pragma unroll
            for (int r = 0; r < 4; ++r) {
                int m = m0 + 64 * wr + 16 * mi + 4 * g + r;
                out[(size_t)m * 1024 + n] = acc[mi][ni][r] + bn;
            }
        }
}

extern "C" void kernel_launch(void* const* d_in, const int* in_sizes, int n_in,
                              void* d_out, int out_size, void* d_ws, size_t ws_size,
                              hipStream_t stream)
{
    const float* query = (const float*)d_in[0];
    const float* key_  = (const float*)d_in[1];
    const float* value = (const float*)d_in[2];
    const float* Wq = (const float*)d_in[3];
    const float* bq = (const float*)d_in[4];
    const float* Wk = (const float*)d_in[5];
    const float* bk = (const float*)d_in[6];
    const float* Wv = (const float*)d_in[7];
    const float* bv = (const float*)d_in[8];
    const float* Wo = (const float*)d_in[9];
    const float* bo = (const float*)d_in[10];
    float* out = (float*)d_out;

    char* p = (char*)d_ws;
    __bf16* Qbuf = (__bf16*)p; p += 8192ull * 1024 * 2;
    __bf16* Kbuf = (__bf16*)p; p += 8192ull * 1024 * 2;
    __bf16* VtB  = (__bf16*)p; p += 64ull * 8192 * 2;
    __bf16* WqT  = (__bf16*)p; p += 1024ull * 1024 * 2;
    __bf16* WkT  = (__bf16*)p; p += 1024ull * 1024 * 2;
    __bf16* WvT  = (__bf16*)p; p += 128ull * 1024 * 2;
    __bf16* WoT  = (__bf16*)p; p += 1024ull * 64 * 2;
    float*  bvP  = (float*)p;  p += 128 * 4;
    __bf16* Oh   = (__bf16*)p; p += 8ull * 16 * 1024 * 64 * 2;
    __bf16* Om   = (__bf16*)p; p += 8192ull * 64 * 2;

    pack_all<<<768, 256, 0, stream>>>(Wq, Wk, Wv, bv, Wo, WqT, WkT, WvT, bvP, WoT);
    proj_qk<<<dim3(64, 8, 2), 256, 0, stream>>>(query, key_, WqT, WkT, bq, bk, Qbuf, Kbuf);
    proj_v<<<128, 256, 0, stream>>>(value, WvT, bvP, VtB);
    attn_kernel<<<dim3(16, 128), 128, 0, stream>>>(Qbuf, Kbuf, VtB, Oh);
    mean_kernel<<<256, 256, 0, stream>>>(Oh, Om);
    out_gemm<<<dim3(64, 8), 256, 0, stream>>>(Om, WoT, bo, out);
}